// Round 4
// baseline (2311.430 us; speedup 1.0000x reference)
//
#include <hip/hip_runtime.h>
#include <hip/hip_bf16.h>
#include <math.h>

using bf16 = __hip_bfloat16;
typedef __attribute__((ext_vector_type(8))) short s8v;
typedef __attribute__((ext_vector_type(4))) float f4v;

#define MTOT 65536   // B*T
#define TLEN 2048
#define NCHUNK 16
#define TCH 128

// params-table float offsets
#define PB_ENC 0
#define PD     256
#define PB1    1792
#define PB2    7936
#define PBNS   9472
#define PBNB   11008
#define PWOUT  12544
#define PBOUT  15104
#define PTOT   15114

__device__ __forceinline__ float b2f(bf16 x) { return __bfloat162float(x); }
__device__ __forceinline__ bf16 f2b(float x) { return __float2bfloat16(x); }

__device__ __forceinline__ float ldf(const void* p, size_t i, int f) {
    return f ? ((const float*)p)[i] : b2f(((const bf16*)p)[i]);
}

__device__ __forceinline__ void ld_g2l(const void* g, void* l) {
    __builtin_amdgcn_global_load_lds(
        (const __attribute__((address_space(1))) void*)g,
        (__attribute__((address_space(3))) void*)l,
        16, 0, 0);
}

// ---------------- dtype detection ----------------
__global__ void detect_k(const unsigned short* __restrict__ x, int* __restrict__ flag) {
    int tid = threadIdx.x;
    int cnt = 0;
    for (int i = tid; i < 8192; i += 256) {
        int e = (x[i] >> 7) & 0xFF;
        if (e == 0 || e == 0xFF) cnt++;
    }
    __shared__ int red[256];
    red[tid] = cnt;
    __syncthreads();
    for (int s = 128; s > 0; s >>= 1) {
        if (tid < s) red[tid] += red[tid + s];
        __syncthreads();
    }
    if (tid == 0) flag[0] = (red[0] >= 2) ? 1 : 0;
}

__global__ void cvt_k(const void* __restrict__ src, bf16* __restrict__ dst, int n,
                      const int* __restrict__ flag) {
    int f = *flag;
    int i = blockIdx.x * 256 + threadIdx.x;
    if (i < n) dst[i] = f2b(ldf(src, i, f));
}

// all small params -> fp32 table
__global__ void cvtparams(const void* b_enc, const void* Dp, const void* b1,
                          const void* b2, const void* bn_s, const void* bn_b,
                          const void* W_out, const void* b_out,
                          float* __restrict__ pf, const int* __restrict__ flag) {
    int f = *flag;
    int i = blockIdx.x * 256 + threadIdx.x;
    if (i < 256)        pf[i] = ldf(b_enc, i, f);
    else if (i < 1792)  pf[i] = ldf(Dp, i - 256, f);
    else if (i < 7936)  pf[i] = ldf(b1, i - 1792, f);
    else if (i < 9472)  pf[i] = ldf(b2, i - 7936, f);
    else if (i < 11008) pf[i] = ldf(bn_s, i - 9472, f);
    else if (i < 12544) pf[i] = ldf(bn_b, i - 11008, f);
    else if (i < 15104) pf[i] = ldf(W_out, i - 12544, f);
    else if (i < PTOT)  pf[i] = ldf(b_out, i - 15104, f);
}

// lambda (fp32) + gamma tables for all 6 layers
__global__ void lamgam_k(const void* __restrict__ nu, const void* __restrict__ th,
                         float* __restrict__ lamb, float* __restrict__ gamt,
                         const int* __restrict__ flag) {
    int f = *flag;
    int g = blockIdx.x * 256 + threadIdx.x;  // 1536
    float nl = ldf(nu, g, f), tl = ldf(th, g, f);
    float mag = expf(-expf(nl));
    float ang = expf(tl);
    lamb[g * 2] = mag * cosf(ang);
    lamb[g * 2 + 1] = mag * sinf(ang);
    gamt[g] = sqrtf(fmaxf(1.f - mag * mag, 1e-12f));
}

// ---------------- GEMM: out[m,n] = sum_k A[m,k]*W[n,k] + epilogue ----------
// 128x128 tile, BK=64, 16x16x32 MFMA, LDS-transposed vector epilogue.
// EPI 0: +biasF -> bf16                         (Bu, BN-folded bias)
// EPI 1: +biasF -> bf16 outB AND outB2          (encoder -> xc, y)
// EPI 2: +Dv[n]*(st_a[n]*aux+st_c[n]) -> bf16   (LRU C-out, BN-folded D-term)
// EPI 5: +biasF + aux -> bf16                   (W2 + residual y -> xc)
template<int EPI>
__global__ __launch_bounds__(256)
void gemm_bt(const bf16* __restrict__ A, int lda,
             const bf16* __restrict__ W, int K,
             bf16* __restrict__ outB, bf16* __restrict__ outB2, int ldo,
             const float* __restrict__ biasF,
             const float* __restrict__ st,
             const float* __restrict__ Dv,
             const bf16* __restrict__ aux)
{
    const int bm = blockIdx.x, bn = blockIdx.y;
    const int tid = threadIdx.x;
    const int lane = tid & 63, wv = tid >> 6;
    const int wm = wv >> 1, wn = wv & 1;
    const int quad = lane >> 4, cl = lane & 15;

    __shared__ __align__(16) char smem[34816];
    short* As = (short*)smem;
    short* Ws = (short*)(smem + 16384);

    f4v acc[4][4];
#pragma unroll
    for (int i = 0; i < 4; i++)
#pragma unroll
        for (int j = 0; j < 4; j++) acc[i][j] = (f4v){0.f, 0.f, 0.f, 0.f};

    const char* Abase = (const char*)(A + (size_t)bm * 128 * lda);
    const char* Wbase = (const char*)(W + (size_t)bn * 128 * K);
    const int rsub = lane >> 3;
    const int swz = ((lane & 7) ^ rsub) * 16;

    for (int kt = 0; kt < K; kt += 64) {
#pragma unroll
        for (int p = 0; p < 4; ++p) {
            int seg = p * 4 + wv;
            const char* ga = Abase + (size_t)(seg * 8 + rsub) * (lda * 2) + kt * 2 + swz;
            ld_g2l(ga, (char*)As + seg * 1024);
            const char* gw = Wbase + (size_t)(seg * 8 + rsub) * (K * 2) + kt * 2 + swz;
            ld_g2l(gw, (char*)Ws + seg * 1024);
        }
        __syncthreads();
#pragma unroll
        for (int kk = 0; kk < 2; ++kk) {
            s8v af[4], bfr[4];
#pragma unroll
            for (int i = 0; i < 4; i++) {
                int r = wm * 64 + i * 16 + cl;
                int poff = (((kk * 4 + quad) ^ (r & 7)) * 8);
                af[i] = *(const s8v*)&As[r * 64 + poff];
            }
#pragma unroll
            for (int j = 0; j < 4; j++) {
                int r = wn * 64 + j * 16 + cl;
                int poff = (((kk * 4 + quad) ^ (r & 7)) * 8);
                bfr[j] = *(const s8v*)&Ws[r * 64 + poff];
            }
#pragma unroll
            for (int i = 0; i < 4; i++)
#pragma unroll
                for (int j = 0; j < 4; j++)
                    acc[i][j] = __builtin_amdgcn_mfma_f32_16x16x32_bf16(af[i], bfr[j], acc[i][j], 0, 0, 0);
        }
        __syncthreads();
    }

    // epilogue: two 64-col passes through padded LDS (stride 68 + wn*36)
    float* ep = (float*)smem;
    const int erow = tid >> 1, es = tid & 1;
    const size_t ld = (size_t)ldo;
#pragma unroll
    for (int p = 0; p < 2; ++p) {
        if (p) __syncthreads();
#pragma unroll
        for (int i = 0; i < 4; i++)
#pragma unroll
            for (int jj = 0; jj < 2; jj++)
#pragma unroll
                for (int r = 0; r < 4; r++) {
                    int row = wm * 64 + i * 16 + quad * 4 + r;
                    ep[row * 68 + wn * 36 + jj * 16 + cl] = acc[i][2 * p + jj][r];
                }
        __syncthreads();
        int m = bm * 128 + erow;
        int nl = es * 64 + 32 * p;
        int n = bn * 128 + nl;
        const float* src = ep + erow * 68 + es * 36;
        float v[32];
#pragma unroll
        for (int q = 0; q < 8; q++) {
            f4v t = *(const f4v*)(src + q * 4);
            v[q * 4] = t[0]; v[q * 4 + 1] = t[1]; v[q * 4 + 2] = t[2]; v[q * 4 + 3] = t[3];
        }
        if (EPI == 0 || EPI == 1 || EPI == 5) {
#pragma unroll
            for (int x = 0; x < 32; x++) v[x] += biasF[n + x];
        }
        if (EPI == 2) {
            const bf16* ap = aux + (size_t)m * ld + n;
#pragma unroll
            for (int q = 0; q < 4; q++) {
                s8v t = *(const s8v*)(ap + q * 8);
#pragma unroll
                for (int e2 = 0; e2 < 8; e2++) {
                    int x = q * 8 + e2;
                    float hb = b2f(((const bf16*)&t)[e2]);
                    v[x] += Dv[n + x] * (st[n + x] * hb + st[256 + n + x]);
                }
            }
        }
        if (EPI == 5) {
            const bf16* ap = aux + (size_t)m * ld + n;
#pragma unroll
            for (int q = 0; q < 4; q++) {
                s8v t = *(const s8v*)(ap + q * 8);
#pragma unroll
                for (int e2 = 0; e2 < 8; e2++)
                    v[q * 8 + e2] += b2f(((const bf16*)&t)[e2]);
            }
        }
        s8v ov[4];
#pragma unroll
        for (int q = 0; q < 4; q++)
#pragma unroll
            for (int e2 = 0; e2 < 8; e2++)
                ((bf16*)&ov[q])[e2] = f2b(v[q * 8 + e2]);
        bf16* dp = outB + (size_t)m * ld + n;
#pragma unroll
        for (int q = 0; q < 4; q++) *(s8v*)(dp + q * 8) = ov[q];
        if (EPI == 1) {
            bf16* dp2 = outB2 + (size_t)m * ld + n;
#pragma unroll
            for (int q = 0; q < 4; q++) *(s8v*)(dp2 + q * 8) = ov[q];
        }
    }
}

// ---------------- fused GLU GEMM: out = (A@Wv^T+bv) * sigmoid(A@Wg^T+bg) ---
__global__ __launch_bounds__(256)
void gemm_glu(const bf16* __restrict__ A,      // lruo [M,256]
              const bf16* __restrict__ Wv,     // w1t rows 0..511
              const bf16* __restrict__ Wg,     // w1t rows 512..1023
              bf16* __restrict__ outB,         // bu [M,512]
              const float* __restrict__ biasF) // b1 layer (1024)
{
    const int bm = blockIdx.x, bn = blockIdx.y;
    const int tid = threadIdx.x;
    const int lane = tid & 63, wv = tid >> 6;
    const int wm = wv >> 1, wn = wv & 1;
    const int quad = lane >> 4, cl = lane & 15;

    __shared__ __align__(16) char smem[49152];
    short* As = (short*)smem;
    short* Vs = (short*)(smem + 16384);
    short* Gs = (short*)(smem + 32768);

    f4v av[4][4], ag[4][4];
#pragma unroll
    for (int i = 0; i < 4; i++)
#pragma unroll
        for (int j = 0; j < 4; j++) { av[i][j] = (f4v){0,0,0,0}; ag[i][j] = (f4v){0,0,0,0}; }

    const char* Abase = (const char*)(A + (size_t)bm * 128 * 256);
    const char* Vbase = (const char*)(Wv + (size_t)bn * 128 * 256);
    const char* Gbase = (const char*)(Wg + (size_t)bn * 128 * 256);
    const int rsub = lane >> 3;
    const int swz = ((lane & 7) ^ rsub) * 16;

    for (int kt = 0; kt < 256; kt += 64) {
#pragma unroll
        for (int p = 0; p < 4; ++p) {
            int seg = p * 4 + wv;
            size_t roff = (size_t)(seg * 8 + rsub) * 512 + kt * 2 + swz;
            ld_g2l(Abase + roff, (char*)As + seg * 1024);
            ld_g2l(Vbase + roff, (char*)Vs + seg * 1024);
            ld_g2l(Gbase + roff, (char*)Gs + seg * 1024);
        }
        __syncthreads();
#pragma unroll
        for (int kk = 0; kk < 2; ++kk) {
            s8v af[4], bv[4], bg[4];
#pragma unroll
            for (int i = 0; i < 4; i++) {
                int r = wm * 64 + i * 16 + cl;
                int poff = (((kk * 4 + quad) ^ (r & 7)) * 8);
                af[i] = *(const s8v*)&As[r * 64 + poff];
            }
#pragma unroll
            for (int j = 0; j < 4; j++) {
                int r = wn * 64 + j * 16 + cl;
                int poff = (((kk * 4 + quad) ^ (r & 7)) * 8);
                bv[j] = *(const s8v*)&Vs[r * 64 + poff];
                bg[j] = *(const s8v*)&Gs[r * 64 + poff];
            }
#pragma unroll
            for (int i = 0; i < 4; i++)
#pragma unroll
                for (int j = 0; j < 4; j++) {
                    av[i][j] = __builtin_amdgcn_mfma_f32_16x16x32_bf16(af[i], bv[j], av[i][j], 0, 0, 0);
                    ag[i][j] = __builtin_amdgcn_mfma_f32_16x16x32_bf16(af[i], bg[j], ag[i][j], 0, 0, 0);
                }
        }
        __syncthreads();
    }

    // epilogue: four 32-col passes; val+gate staged through padded LDS
    float* epv = (float*)smem;
    float* epg = (float*)(smem + 18432);
    const int erow = tid >> 1, es = tid & 1;
#pragma unroll
    for (int p = 0; p < 4; ++p) {
        if (p) __syncthreads();
#pragma unroll
        for (int i = 0; i < 4; i++)
#pragma unroll
            for (int r = 0; r < 4; r++) {
                int row = wm * 64 + i * 16 + quad * 4 + r;
                int o = row * 36 + wn * 20 + cl;
                epv[o] = av[i][p][r];
                epg[o] = ag[i][p][r];
            }
        __syncthreads();
        int m = bm * 128 + erow;
        int nl = es * 64 + p * 16;
        int n = bn * 128 + nl;
        const float* sv = epv + erow * 36 + es * 20;
        const float* sg = epg + erow * 36 + es * 20;
        float vv[16];
#pragma unroll
        for (int q = 0; q < 4; q++) {
            f4v tv = *(const f4v*)(sv + q * 4);
            f4v tg = *(const f4v*)(sg + q * 4);
#pragma unroll
            for (int e2 = 0; e2 < 4; e2++) {
                int x = q * 4 + e2;
                float val = tv[e2] + biasF[n + x];
                float gat = tg[e2] + biasF[512 + n + x];
                vv[x] = val / (1.f + expf(-gat));
            }
        }
        s8v ov[2];
#pragma unroll
        for (int q = 0; q < 2; q++)
#pragma unroll
            for (int e2 = 0; e2 < 8; e2++)
                ((bf16*)&ov[q])[e2] = f2b(vv[q * 8 + e2]);
        bf16* dp = outB + (size_t)m * 512 + n;
        *(s8v*)(dp) = ov[0];
        *(s8v*)(dp + 8) = ov[1];
    }
}

// ---------------- BatchNorm stats (two-pass, transposed partials) ----------
__global__ void bn_part(const bf16* __restrict__ x, float* __restrict__ part) {
    int e = threadIdx.x, b = blockIdx.x;  // 256 blocks
    size_t base = (size_t)b * 256;
    float s = 0.f, s2 = 0.f;
    for (int r = 0; r < 256; r++) {
        float v = b2f(x[(base + r) * 256 + e]);
        s += v; s2 += v * v;
    }
    part[(size_t)e * 256 + b] = s;
    part[65536 + (size_t)e * 256 + b] = s2;
}

// st[0..255] = a (scale), st[256..511] = c (offset):  BN(x)[e] = a[e]*x + c[e]
__global__ void bn_finish(const float* __restrict__ part, const float* __restrict__ pf,
                          int layer, float* __restrict__ st) {
    int e = threadIdx.x;
    const float* p1 = part + (size_t)e * 256;
    const float* p2 = part + 65536 + (size_t)e * 256;
    float s = 0.f, s2 = 0.f;
    for (int b = 0; b < 256; b += 4) {
        f4v t1 = *(const f4v*)(p1 + b);
        f4v t2 = *(const f4v*)(p2 + b);
        s += t1[0] + t1[1] + t1[2] + t1[3];
        s2 += t2[0] + t2[1] + t2[2] + t2[3];
    }
    float mu = s * (1.f / 65536.f);
    float var = s2 * (1.f / 65536.f) - mu * mu;
    float a = rsqrtf(var + 1e-5f) * pf[PBNS + layer * 256 + e];
    st[e] = a;
    st[256 + e] = pf[PBNB + layer * 256 + e] - mu * a;
}

// ---------------- per-layer weight packing (single dispatch) ----------------
// blocks 0..511: wb (BN-scale folded), 512..1023: wc, 1024..2047: w1t,
// 2048..2559: w2t, 2560..2561: bu_bias
__global__ void pack_layer(const void* __restrict__ B_re, const void* __restrict__ B_im,
                           const void* __restrict__ C_re, const void* __restrict__ C_im,
                           const void* __restrict__ W1, const void* __restrict__ W2,
                           int layer, const float* __restrict__ st,
                           const float* __restrict__ gamt,
                           bf16* __restrict__ wb, bf16* __restrict__ wc,
                           bf16* __restrict__ w1t, bf16* __restrict__ w2t,
                           float* __restrict__ bubias, const int* __restrict__ flag) {
    int f = *flag;
    int blk = blockIdx.x, tid = threadIdx.x;
    size_t offBC = (size_t)layer * 65536;
    if (blk < 512) {
        int g = blk * 256 + tid;
        int n = g >> 8, e = g & 255, h = n & 255;
        const void* src = (n < 256) ? B_re : B_im;
        wb[g] = f2b(st[e] * gamt[layer * 256 + h] * ldf(src, offBC + (size_t)h * 256 + e, f));
    } else if (blk < 1024) {
        int g = (blk - 512) * 256 + tid;
        int e = g >> 9, k = g & 511;
        float v = (k < 256) ? ldf(C_re, offBC + (size_t)e * 256 + k, f)
                            : -ldf(C_im, offBC + (size_t)e * 256 + (k - 256), f);
        wc[g] = f2b(v);
    } else if (blk < 2048) {
        int g = (blk - 1024) * 256 + tid;
        int n = g >> 8, k = g & 255;
        w1t[g] = f2b(ldf(W1, (size_t)layer * 262144 + (size_t)k * 1024 + n, f));
    } else if (blk < 2560) {
        int g = (blk - 2048) * 256 + tid;
        int n = g >> 9, k = g & 511;
        w2t[g] = f2b(ldf(W2, (size_t)layer * 131072 + (size_t)k * 256 + n, f));
    } else {
        int n = (blk - 2560) * 256 + tid;  // 0..511
        int h = n & 255;
        const void* src = (n < 256) ? B_re : B_im;
        float gam = gamt[layer * 256 + h];
        float s = 0.f;
        for (int e = 0; e < 256; e++)
            s += st[256 + e] * ldf(src, offBC + (size_t)h * 256 + e, f);
        bubias[n] = s * gam;
    }
}

// ---------------- LRU scan (chunked, in-place over bu) ----------------
__global__ void lru_carry(const bf16* __restrict__ bu, const float* __restrict__ lam,
                          float* __restrict__ carry) {
    int g = blockIdx.x * 256 + threadIdx.x;
    int h = g & 255, c = (g >> 8) & 15, b = g >> 12;
    float lr = lam[h * 2], li = lam[h * 2 + 1];
    float sr = 0.f, si = 0.f;
    const bf16* p = bu + ((size_t)(b * TLEN + c * TCH)) * 512 + h;
    for (int t = 0; t < TCH; t++) {
        float ur = b2f(p[0]), ui = b2f(p[256]);
        float nr = lr * sr - li * si + ur;
        si = lr * si + li * sr + ui;
        sr = nr;
        p += 512;
    }
    carry[(size_t)g * 2] = sr;
    carry[(size_t)g * 2 + 1] = si;
}

__global__ void lru_prefix(const float* __restrict__ carry, float* __restrict__ pre,
                           const float* __restrict__ lam) {
    int g = blockIdx.x * 256 + threadIdx.x;  // 8192
    int h = g & 255, b = g >> 8;
    float pr = lam[h * 2], pi = lam[h * 2 + 1];
    for (int k = 0; k < 7; k++) { float nr = pr * pr - pi * pi; pi = 2.f * pr * pi; pr = nr; }
    float er = 0.f, ei = 0.f;
    for (int c = 0; c < NCHUNK; c++) {
        size_t idx = ((size_t)(b * NCHUNK + c) * 256 + h) * 2;
        pre[idx] = er; pre[idx + 1] = ei;
        float cr = carry[idx], ci = carry[idx + 1];
        float nr = pr * er - pi * ei + cr;
        ei = pr * ei + pi * er + ci;
        er = nr;
    }
}

__global__ void lru_final(bf16* __restrict__ bu, const float* __restrict__ pre,
                          const float* __restrict__ lam) {
    int g = blockIdx.x * 256 + threadIdx.x;
    int h = g & 255, c = (g >> 8) & 15, b = g >> 12;
    float lr = lam[h * 2], li = lam[h * 2 + 1];
    float sr = pre[(size_t)g * 2], si = pre[(size_t)g * 2 + 1];
    bf16* p = bu + ((size_t)(b * TLEN + c * TCH)) * 512 + h;
    for (int t = 0; t < TCH; t++) {
        float ur = b2f(p[0]), ui = b2f(p[256]);
        float nr = lr * sr - li * si + ur;
        si = lr * si + li * sr + ui;
        sr = nr;
        p[0] = f2b(sr);
        p[256] = f2b(si);
        p += 512;
    }
}

// ---------------- pooling + head ----------------
__global__ void pool_part(const bf16* __restrict__ xc, float* __restrict__ part) {
    int blk = blockIdx.x;  // 512
    int b = blk >> 4, tc = blk & 15;
    int e = threadIdx.x;
    const bf16* p = xc + ((size_t)b * TLEN + tc * TCH) * 256 + e;
    float s = 0.f;
    for (int r = 0; r < TCH; r++) { s += b2f(*p); p += 256; }
    part[(size_t)blk * 256 + e] = s;
}

__global__ void head_k(const float* __restrict__ part, const float* __restrict__ pf,
                       void* __restrict__ out, const int* __restrict__ flag) {
    int b = blockIdx.x;
    int tid = threadIdx.x;
    __shared__ float sp[256];
    __shared__ float red[160];
    float s = 0.f;
    for (int c = 0; c < 16; c++) s += part[((size_t)(b * 16 + c)) * 256 + tid];
    sp[tid] = s * (1.f / 2048.f);
    __syncthreads();
    if (tid < 160) {
        int o = tid >> 4, sg = tid & 15;
        float a = 0.f;
        for (int e = sg; e < 256; e += 16) a += sp[e] * pf[PWOUT + e * 10 + o];
        red[tid] = a;
    }
    __syncthreads();
    if (tid < 10) {
        float acc = pf[PBOUT + tid];
        for (int sg = 0; sg < 16; sg++) acc += red[tid * 16 + sg];
        if (*flag) ((float*)out)[b * 10 + tid] = acc;
        else       ((bf16*)out)[b * 10 + tid] = f2b(acc);
    }
}

__global__ void pack_wt_enc(const void* __restrict__ W_enc, bf16* __restrict__ out,
                            const int* __restrict__ flag) {
    int f = *flag;
    int g = blockIdx.x * 256 + threadIdx.x;  // 16384
    int n = g >> 6, k = g & 63;
    out[g] = f2b(ldf(W_enc, (size_t)k * 256 + n, f));
}

extern "C" void kernel_launch(void* const* d_in, const int* in_sizes, int n_in,
                              void* d_out, int out_size, void* d_ws, size_t ws_size,
                              hipStream_t stream) {
    (void)in_sizes; (void)n_in; (void)out_size; (void)ws_size;
    const void* x      = d_in[0];
    const void* W_enc  = d_in[1];
    const void* b_enc  = d_in[2];
    const void* nu_log = d_in[3];
    const void* th_log = d_in[4];
    const void* B_re   = d_in[5];
    const void* B_im   = d_in[6];
    const void* C_re   = d_in[7];
    const void* C_im   = d_in[8];
    const void* Dp     = d_in[9];
    const void* W1     = d_in[10];
    const void* b1     = d_in[11];
    const void* W2     = d_in[12];
    const void* b2     = d_in[13];
    const void* bn_s   = d_in[14];
    const void* bn_b   = d_in[15];
    const void* W_out  = d_in[16];
    const void* b_out  = d_in[17];

    // workspace layout (~171 MB)
    char* w = (char*)d_ws;
    bf16* xc   = (bf16*)w; w += (size_t)MTOT * 256 * 2;
    bf16* y    = (bf16*)w; w += (size_t)MTOT * 256 * 2;
    bf16* lruo = (bf16*)w; w += (size_t)MTOT * 256 * 2;
    bf16* bu   = (bf16*)w; w += (size_t)MTOT * 512 * 2;
    float* bnpart = (float*)w; w += 524288;
    float* carry  = (float*)w; w += 1048576;
    float* pre    = (float*)w; w += 1048576;
    float* part   = (float*)w; w += 524288;
    float* lamb   = (float*)w; w += 12288;
    float* gamt   = (float*)w; w += 6144;
    float* pf     = (float*)w; w += 65536;
    float* st     = (float*)w; w += 2048;
    float* bubias = (float*)w; w += 2048;
    int*   flag   = (int*)w;  w += 256;
    bf16* wt_enc = (bf16*)w; w += 32768;
    bf16* wb  = (bf16*)w; w += 262144;
    bf16* wc  = (bf16*)w; w += 262144;
    bf16* w1t = (bf16*)w; w += 524288;
    bf16* w2t = (bf16*)w; w += 262144;
    bf16* xb = bu;  // x bf16 copy aliases bu (dead until first Bu GEMM)

    dim3 blk(256);
    detect_k<<<1, blk, 0, stream>>>((const unsigned short*)x, flag);
    cvt_k<<<16384, blk, 0, stream>>>(x, xb, 4194304, flag);
    cvtparams<<<60, blk, 0, stream>>>(b_enc, Dp, b1, b2, bn_s, bn_b, W_out, b_out, pf, flag);
    lamgam_k<<<6, blk, 0, stream>>>(nu_log, th_log, lamb, gamt, flag);
    pack_wt_enc<<<64, blk, 0, stream>>>(W_enc, wt_enc, flag);

    // encoder: [M,64] @ W_enc^T + b_enc -> xc and y
    gemm_bt<1><<<dim3(512, 2), blk, 0, stream>>>(xb, 64, wt_enc, 64, xc, y, 256,
                                                 pf + PB_ENC, nullptr, nullptr, nullptr);
    for (int i = 0; i < 6; ++i) {
        bn_part<<<256, blk, 0, stream>>>(xc, bnpart);
        bn_finish<<<1, blk, 0, stream>>>(bnpart, pf, i, st);
        pack_layer<<<2562, blk, 0, stream>>>(B_re, B_im, C_re, C_im, W1, W2, i, st, gamt,
                                             wb, wc, w1t, w2t, bubias, flag);
        // Bu = xc @ (a*gamma*B)^T + bu_bias  (BN folded) -> [M,512]
        gemm_bt<0><<<dim3(512, 4), blk, 0, stream>>>(xc, 256, wb, 256, bu, nullptr, 512,
                                                     bubias, nullptr, nullptr, nullptr);
        lru_carry<<<512, blk, 0, stream>>>(bu, lamb + i * 512, carry);
        lru_prefix<<<32, blk, 0, stream>>>(carry, pre, lamb + i * 512);
        lru_final<<<512, blk, 0, stream>>>(bu, pre, lamb + i * 512);
        // lruo = hs @ [C_re;-C_im]^T + D*(a*xc+c)
        gemm_bt<2><<<dim3(512, 2), blk, 0, stream>>>(bu, 512, wc, 512, lruo, nullptr, 256,
                                                     nullptr, st, pf + PD + i * 256, xc);
        // glu = (lruo@W1v + b1v) * sigmoid(lruo@W1g + b1g) -> bu [M,512]
        gemm_glu<<<dim3(512, 4), blk, 0, stream>>>(lruo, w1t, w1t + 131072, bu,
                                                   pf + PB1 + i * 1024);
        // xc = glu @ W2^T + b2 + y
        gemm_bt<5><<<dim3(512, 2), blk, 0, stream>>>(bu, 512, w2t, 512, xc, nullptr, 256,
                                                     pf + PB2 + i * 256, nullptr, nullptr, y);
    }
    pool_part<<<512, blk, 0, stream>>>(xc, part);
    head_k<<<32, blk, 0, stream>>>(part, pf, d_out, flag);
}

// Round 5
// 2050.559 us; speedup vs baseline: 1.1272x; 1.1272x over previous
//
#include <hip/hip_runtime.h>
#include <hip/hip_bf16.h>
#include <math.h>

using bf16 = __hip_bfloat16;
typedef __attribute__((ext_vector_type(8))) short s8v;
typedef __attribute__((ext_vector_type(4))) short s4v;
typedef __attribute__((ext_vector_type(4))) float f4v;

#define MTOT 65536   // B*T
#define TLEN 2048
#define NCHUNK 16
#define TCH 128

// params-table float offsets
#define PB_ENC 0
#define PD     256
#define PB1    1792
#define PB2    7936
#define PBNS   9472
#define PBNB   11008
#define PWOUT  12544
#define PBOUT  15104
#define PTOT   15114

__device__ __forceinline__ float b2f(bf16 x) { return __bfloat162float(x); }
__device__ __forceinline__ bf16 f2b(float x) { return __float2bfloat16(x); }

__device__ __forceinline__ float ldf(const void* p, size_t i, int f) {
    return f ? ((const float*)p)[i] : b2f(((const bf16*)p)[i]);
}

__device__ __forceinline__ void ld_g2l(const void* g, void* l) {
    __builtin_amdgcn_global_load_lds(
        (const __attribute__((address_space(1))) void*)g,
        (__attribute__((address_space(3))) void*)l,
        16, 0, 0);
}

// ---------------- dtype detection ----------------
__global__ void detect_k(const unsigned short* __restrict__ x, int* __restrict__ flag) {
    int tid = threadIdx.x;
    int cnt = 0;
    for (int i = tid; i < 8192; i += 256) {
        int e = (x[i] >> 7) & 0xFF;
        if (e == 0 || e == 0xFF) cnt++;
    }
    __shared__ int red[256];
    red[tid] = cnt;
    __syncthreads();
    for (int s = 128; s > 0; s >>= 1) {
        if (tid < s) red[tid] += red[tid + s];
        __syncthreads();
    }
    if (tid == 0) flag[0] = (red[0] >= 2) ? 1 : 0;
}

__global__ void cvt_k(const void* __restrict__ src, bf16* __restrict__ dst, int n,
                      const int* __restrict__ flag) {
    int f = *flag;
    int i = blockIdx.x * 256 + threadIdx.x;
    if (i < n) dst[i] = f2b(ldf(src, i, f));
}

// all small params -> fp32 table
__global__ void cvtparams(const void* b_enc, const void* Dp, const void* b1,
                          const void* b2, const void* bn_s, const void* bn_b,
                          const void* W_out, const void* b_out,
                          float* __restrict__ pf, const int* __restrict__ flag) {
    int f = *flag;
    int i = blockIdx.x * 256 + threadIdx.x;
    if (i < 256)        pf[i] = ldf(b_enc, i, f);
    else if (i < 1792)  pf[i] = ldf(Dp, i - 256, f);
    else if (i < 7936)  pf[i] = ldf(b1, i - 1792, f);
    else if (i < 9472)  pf[i] = ldf(b2, i - 7936, f);
    else if (i < 11008) pf[i] = ldf(bn_s, i - 9472, f);
    else if (i < 12544) pf[i] = ldf(bn_b, i - 11008, f);
    else if (i < 15104) pf[i] = ldf(W_out, i - 12544, f);
    else if (i < PTOT)  pf[i] = ldf(b_out, i - 15104, f);
}

// lambda (fp32) + gamma tables for all 6 layers
__global__ void lamgam_k(const void* __restrict__ nu, const void* __restrict__ th,
                         float* __restrict__ lamb, float* __restrict__ gamt,
                         const int* __restrict__ flag) {
    int f = *flag;
    int g = blockIdx.x * 256 + threadIdx.x;  // 1536
    float nl = ldf(nu, g, f), tl = ldf(th, g, f);
    float mag = expf(-expf(nl));
    float ang = expf(tl);
    lamb[g * 2] = mag * cosf(ang);
    lamb[g * 2 + 1] = mag * sinf(ang);
    gamt[g] = sqrtf(fmaxf(1.f - mag * mag, 1e-12f));
}

// ---------------- GEMM: out[m,n] = sum_k A[m,k]*W[n,k] + epilogue ----------
// 128x128 tile, BK=64, 16x16x32 MFMA. Operands SWAPPED in the mfma call so
// the C-tile comes out transposed: lane holds m = tile_m + cl (fixed) and
// n = tile_n + quad*4 + reg (4 consecutive) -> 8B vector stores, no LDS
// staging, no transpose cost.
// EPI 0: +biasF -> bf16                         (Bu, BN-folded bias)
// EPI 1: +biasF -> bf16 outB AND outB2          (encoder -> xc, y)
// EPI 2: +Dv[n]*(st_a[n]*aux+st_c[n]) -> bf16   (LRU C-out, BN-folded D-term)
// EPI 5: +biasF + aux -> bf16                   (W2 + residual y -> xc)
template<int EPI>
__global__ __launch_bounds__(256)
void gemm_bt(const bf16* __restrict__ A, int lda,
             const bf16* __restrict__ W, int K,
             bf16* __restrict__ outB, bf16* __restrict__ outB2, int ldo,
             const float* __restrict__ biasF,
             const float* __restrict__ st,
             const float* __restrict__ Dv,
             const bf16* __restrict__ aux)
{
    const int bm = blockIdx.x, bn = blockIdx.y;
    const int tid = threadIdx.x;
    const int lane = tid & 63, wv = tid >> 6;
    const int wm = wv >> 1, wn = wv & 1;
    const int quad = lane >> 4, cl = lane & 15;

    __shared__ __align__(16) short As[128 * 64];
    __shared__ __align__(16) short Ws[128 * 64];

    f4v acc[4][4];
#pragma unroll
    for (int i = 0; i < 4; i++)
#pragma unroll
        for (int j = 0; j < 4; j++) acc[i][j] = (f4v){0.f, 0.f, 0.f, 0.f};

    const char* Abase = (const char*)(A + (size_t)bm * 128 * lda);
    const char* Wbase = (const char*)(W + (size_t)bn * 128 * K);
    const int rsub = lane >> 3;
    const int swz = ((lane & 7) ^ rsub) * 16;

    for (int kt = 0; kt < K; kt += 64) {
#pragma unroll
        for (int p = 0; p < 4; ++p) {
            int seg = p * 4 + wv;
            const char* ga = Abase + (size_t)(seg * 8 + rsub) * (lda * 2) + kt * 2 + swz;
            ld_g2l(ga, (char*)As + seg * 1024);
            const char* gw = Wbase + (size_t)(seg * 8 + rsub) * (K * 2) + kt * 2 + swz;
            ld_g2l(gw, (char*)Ws + seg * 1024);
        }
        __syncthreads();
#pragma unroll
        for (int kk = 0; kk < 2; ++kk) {
            s8v af[4], bfr[4];
#pragma unroll
            for (int i = 0; i < 4; i++) {
                int r = wm * 64 + i * 16 + cl;
                int poff = (((kk * 4 + quad) ^ (r & 7)) * 8);
                af[i] = *(const s8v*)&As[r * 64 + poff];
            }
#pragma unroll
            for (int j = 0; j < 4; j++) {
                int r = wn * 64 + j * 16 + cl;
                int poff = (((kk * 4 + quad) ^ (r & 7)) * 8);
                bfr[j] = *(const s8v*)&Ws[r * 64 + poff];
            }
            // swapped operands: acc = W_frag * A_frag -> C^T tile layout
#pragma unroll
            for (int i = 0; i < 4; i++)
#pragma unroll
                for (int j = 0; j < 4; j++)
                    acc[i][j] = __builtin_amdgcn_mfma_f32_16x16x32_bf16(bfr[j], af[i], acc[i][j], 0, 0, 0);
        }
        __syncthreads();
    }

    // register-direct epilogue: lane holds m = mBase+i*16, n = nBase+j*16+{0..3}
    const size_t ld = (size_t)ldo;
    const int mBase = bm * 128 + wm * 64 + cl;
    const int nBase = bn * 128 + wn * 64 + quad * 4;
#pragma unroll
    for (int j = 0; j < 4; j++) {
        const int n = nBase + j * 16;
        f4v bb, dv, sa, sc;
        if (EPI == 0 || EPI == 1 || EPI == 5) bb = *(const f4v*)(biasF + n);
        if (EPI == 2) {
            dv = *(const f4v*)(Dv + n);
            sa = *(const f4v*)(st + n);
            sc = *(const f4v*)(st + 256 + n);
        }
#pragma unroll
        for (int i = 0; i < 4; i++) {
            const int m = mBase + i * 16;
            const size_t idx = (size_t)m * ld + n;
            f4v v = acc[i][j];
            if (EPI == 0 || EPI == 1 || EPI == 5) {
#pragma unroll
                for (int e = 0; e < 4; e++) v[e] += bb[e];
            }
            if (EPI == 2) {
                s4v a = *(const s4v*)(aux + idx);
#pragma unroll
                for (int e = 0; e < 4; e++)
                    v[e] += dv[e] * (sa[e] * b2f(((const bf16*)&a)[e]) + sc[e]);
            }
            if (EPI == 5) {
                s4v a = *(const s4v*)(aux + idx);
#pragma unroll
                for (int e = 0; e < 4; e++) v[e] += b2f(((const bf16*)&a)[e]);
            }
            s4v o;
#pragma unroll
            for (int e = 0; e < 4; e++) ((bf16*)&o)[e] = f2b(v[e]);
            *(s4v*)(outB + idx) = o;
            if (EPI == 1) *(s4v*)(outB2 + idx) = o;
        }
    }
}

// ---------------- fused GLU GEMM: out = (A@Wv^T+bv) * sigmoid(A@Wg^T+bg) ---
// Same swapped-operand layout; GLU combined entirely in registers.
__global__ __launch_bounds__(256)
void gemm_glu(const bf16* __restrict__ A,      // lruo [M,256]
              const bf16* __restrict__ Wv,     // w1t rows 0..511
              const bf16* __restrict__ Wg,     // w1t rows 512..1023
              bf16* __restrict__ outB,         // bu [M,512]
              const float* __restrict__ biasF) // b1 layer (1024)
{
    const int bm = blockIdx.x, bn = blockIdx.y;
    const int tid = threadIdx.x;
    const int lane = tid & 63, wv = tid >> 6;
    const int wm = wv >> 1, wn = wv & 1;
    const int quad = lane >> 4, cl = lane & 15;

    __shared__ __align__(16) short As[128 * 64];
    __shared__ __align__(16) short Vs[128 * 64];
    __shared__ __align__(16) short Gs[128 * 64];

    f4v av[4][4], ag[4][4];
#pragma unroll
    for (int i = 0; i < 4; i++)
#pragma unroll
        for (int j = 0; j < 4; j++) { av[i][j] = (f4v){0,0,0,0}; ag[i][j] = (f4v){0,0,0,0}; }

    const char* Abase = (const char*)(A + (size_t)bm * 128 * 256);
    const char* Vbase = (const char*)(Wv + (size_t)bn * 128 * 256);
    const char* Gbase = (const char*)(Wg + (size_t)bn * 128 * 256);
    const int rsub = lane >> 3;
    const int swz = ((lane & 7) ^ rsub) * 16;

    for (int kt = 0; kt < 256; kt += 64) {
#pragma unroll
        for (int p = 0; p < 4; ++p) {
            int seg = p * 4 + wv;
            size_t roff = (size_t)(seg * 8 + rsub) * 512 + kt * 2 + swz;
            ld_g2l(Abase + roff, (char*)As + seg * 1024);
            ld_g2l(Vbase + roff, (char*)Vs + seg * 1024);
            ld_g2l(Gbase + roff, (char*)Gs + seg * 1024);
        }
        __syncthreads();
#pragma unroll
        for (int kk = 0; kk < 2; ++kk) {
            s8v af[4], bv[4], bg[4];
#pragma unroll
            for (int i = 0; i < 4; i++) {
                int r = wm * 64 + i * 16 + cl;
                int poff = (((kk * 4 + quad) ^ (r & 7)) * 8);
                af[i] = *(const s8v*)&As[r * 64 + poff];
            }
#pragma unroll
            for (int j = 0; j < 4; j++) {
                int r = wn * 64 + j * 16 + cl;
                int poff = (((kk * 4 + quad) ^ (r & 7)) * 8);
                bv[j] = *(const s8v*)&Vs[r * 64 + poff];
                bg[j] = *(const s8v*)&Gs[r * 64 + poff];
            }
#pragma unroll
            for (int i = 0; i < 4; i++)
#pragma unroll
                for (int j = 0; j < 4; j++) {
                    av[i][j] = __builtin_amdgcn_mfma_f32_16x16x32_bf16(bv[j], af[i], av[i][j], 0, 0, 0);
                    ag[i][j] = __builtin_amdgcn_mfma_f32_16x16x32_bf16(bg[j], af[i], ag[i][j], 0, 0, 0);
                }
        }
        __syncthreads();
    }

    const int mBase = bm * 128 + wm * 64 + cl;
    const int nBase = bn * 128 + wn * 64 + quad * 4;
#pragma unroll
    for (int j = 0; j < 4; j++) {
        const int n = nBase + j * 16;
        f4v bv4 = *(const f4v*)(biasF + n);
        f4v bg4 = *(const f4v*)(biasF + 512 + n);
#pragma unroll
        for (int i = 0; i < 4; i++) {
            const int m = mBase + i * 16;
            s4v o;
#pragma unroll
            for (int e = 0; e < 4; e++) {
                float val = av[i][j][e] + bv4[e];
                float gat = ag[i][j][e] + bg4[e];
                ((bf16*)&o)[e] = f2b(val / (1.f + expf(-gat)));
            }
            *(s4v*)(outB + (size_t)m * 512 + n) = o;
        }
    }
}

// ---------------- BatchNorm stats (two-pass, transposed partials) ----------
__global__ void bn_part(const bf16* __restrict__ x, float* __restrict__ part) {
    int e = threadIdx.x, b = blockIdx.x;  // 256 blocks
    size_t base = (size_t)b * 256;
    float s = 0.f, s2 = 0.f;
    for (int r = 0; r < 256; r++) {
        float v = b2f(x[(base + r) * 256 + e]);
        s += v; s2 += v * v;
    }
    part[(size_t)e * 256 + b] = s;
    part[65536 + (size_t)e * 256 + b] = s2;
}

// st[0..255] = a (scale), st[256..511] = c (offset):  BN(x)[e] = a[e]*x + c[e]
__global__ void bn_finish(const float* __restrict__ part, const float* __restrict__ pf,
                          int layer, float* __restrict__ st) {
    int e = threadIdx.x;
    const float* p1 = part + (size_t)e * 256;
    const float* p2 = part + 65536 + (size_t)e * 256;
    float s = 0.f, s2 = 0.f;
    for (int b = 0; b < 256; b += 4) {
        f4v t1 = *(const f4v*)(p1 + b);
        f4v t2 = *(const f4v*)(p2 + b);
        s += t1[0] + t1[1] + t1[2] + t1[3];
        s2 += t2[0] + t2[1] + t2[2] + t2[3];
    }
    float mu = s * (1.f / 65536.f);
    float var = s2 * (1.f / 65536.f) - mu * mu;
    float a = rsqrtf(var + 1e-5f) * pf[PBNS + layer * 256 + e];
    st[e] = a;
    st[256 + e] = pf[PBNB + layer * 256 + e] - mu * a;
}

// ---------------- per-layer weight packing (single dispatch) ----------------
__global__ void pack_layer(const void* __restrict__ B_re, const void* __restrict__ B_im,
                           const void* __restrict__ C_re, const void* __restrict__ C_im,
                           const void* __restrict__ W1, const void* __restrict__ W2,
                           int layer, const float* __restrict__ st,
                           const float* __restrict__ gamt,
                           bf16* __restrict__ wb, bf16* __restrict__ wc,
                           bf16* __restrict__ w1t, bf16* __restrict__ w2t,
                           float* __restrict__ bubias, const int* __restrict__ flag) {
    int f = *flag;
    int blk = blockIdx.x, tid = threadIdx.x;
    size_t offBC = (size_t)layer * 65536;
    if (blk < 512) {
        int g = blk * 256 + tid;
        int n = g >> 8, e = g & 255, h = n & 255;
        const void* src = (n < 256) ? B_re : B_im;
        wb[g] = f2b(st[e] * gamt[layer * 256 + h] * ldf(src, offBC + (size_t)h * 256 + e, f));
    } else if (blk < 1024) {
        int g = (blk - 512) * 256 + tid;
        int e = g >> 9, k = g & 511;
        float v = (k < 256) ? ldf(C_re, offBC + (size_t)e * 256 + k, f)
                            : -ldf(C_im, offBC + (size_t)e * 256 + (k - 256), f);
        wc[g] = f2b(v);
    } else if (blk < 2048) {
        int g = (blk - 1024) * 256 + tid;
        int n = g >> 8, k = g & 255;
        w1t[g] = f2b(ldf(W1, (size_t)layer * 262144 + (size_t)k * 1024 + n, f));
    } else if (blk < 2560) {
        int g = (blk - 2048) * 256 + tid;
        int n = g >> 9, k = g & 511;
        w2t[g] = f2b(ldf(W2, (size_t)layer * 131072 + (size_t)k * 256 + n, f));
    } else {
        int n = (blk - 2560) * 256 + tid;  // 0..511
        int h = n & 255;
        const void* src = (n < 256) ? B_re : B_im;
        float gam = gamt[layer * 256 + h];
        float s = 0.f;
        for (int e = 0; e < 256; e++)
            s += st[256 + e] * ldf(src, offBC + (size_t)h * 256 + e, f);
        bubias[n] = s * gam;
    }
}

// ---------------- LRU scan (chunked, in-place over bu) ----------------
__global__ void lru_carry(const bf16* __restrict__ bu, const float* __restrict__ lam,
                          float* __restrict__ carry) {
    int g = blockIdx.x * 256 + threadIdx.x;
    int h = g & 255, c = (g >> 8) & 15, b = g >> 12;
    float lr = lam[h * 2], li = lam[h * 2 + 1];
    float sr = 0.f, si = 0.f;
    const bf16* p = bu + ((size_t)(b * TLEN + c * TCH)) * 512 + h;
    for (int t = 0; t < TCH; t++) {
        float ur = b2f(p[0]), ui = b2f(p[256]);
        float nr = lr * sr - li * si + ur;
        si = lr * si + li * sr + ui;
        sr = nr;
        p += 512;
    }
    carry[(size_t)g * 2] = sr;
    carry[(size_t)g * 2 + 1] = si;
}

__global__ void lru_prefix(const float* __restrict__ carry, float* __restrict__ pre,
                           const float* __restrict__ lam) {
    int g = blockIdx.x * 256 + threadIdx.x;  // 8192
    int h = g & 255, b = g >> 8;
    float pr = lam[h * 2], pi = lam[h * 2 + 1];
    for (int k = 0; k < 7; k++) { float nr = pr * pr - pi * pi; pi = 2.f * pr * pi; pr = nr; }
    float er = 0.f, ei = 0.f;
    for (int c = 0; c < NCHUNK; c++) {
        size_t idx = ((size_t)(b * NCHUNK + c) * 256 + h) * 2;
        pre[idx] = er; pre[idx + 1] = ei;
        float cr = carry[idx], ci = carry[idx + 1];
        float nr = pr * er - pi * ei + cr;
        ei = pr * ei + pi * er + ci;
        er = nr;
    }
}

__global__ void lru_final(bf16* __restrict__ bu, const float* __restrict__ pre,
                          const float* __restrict__ lam) {
    int g = blockIdx.x * 256 + threadIdx.x;
    int h = g & 255, c = (g >> 8) & 15, b = g >> 12;
    float lr = lam[h * 2], li = lam[h * 2 + 1];
    float sr = pre[(size_t)g * 2], si = pre[(size_t)g * 2 + 1];
    bf16* p = bu + ((size_t)(b * TLEN + c * TCH)) * 512 + h;
    for (int t = 0; t < TCH; t++) {
        float ur = b2f(p[0]), ui = b2f(p[256]);
        float nr = lr * sr - li * si + ur;
        si = lr * si + li * sr + ui;
        sr = nr;
        p[0] = f2b(sr);
        p[256] = f2b(si);
        p += 512;
    }
}

// ---------------- pooling + head ----------------
__global__ void pool_part(const bf16* __restrict__ xc, float* __restrict__ part) {
    int blk = blockIdx.x;  // 512
    int b = blk >> 4, tc = blk & 15;
    int e = threadIdx.x;
    const bf16* p = xc + ((size_t)b * TLEN + tc * TCH) * 256 + e;
    float s = 0.f;
    for (int r = 0; r < TCH; r++) { s += b2f(*p); p += 256; }
    part[(size_t)blk * 256 + e] = s;
}

__global__ void head_k(const float* __restrict__ part, const float* __restrict__ pf,
                       void* __restrict__ out, const int* __restrict__ flag) {
    int b = blockIdx.x;
    int tid = threadIdx.x;
    __shared__ float sp[256];
    __shared__ float red[160];
    float s = 0.f;
    for (int c = 0; c < 16; c++) s += part[((size_t)(b * 16 + c)) * 256 + tid];
    sp[tid] = s * (1.f / 2048.f);
    __syncthreads();
    if (tid < 160) {
        int o = tid >> 4, sg = tid & 15;
        float a = 0.f;
        for (int e = sg; e < 256; e += 16) a += sp[e] * pf[PWOUT + e * 10 + o];
        red[tid] = a;
    }
    __syncthreads();
    if (tid < 10) {
        float acc = pf[PBOUT + tid];
        for (int sg = 0; sg < 16; sg++) acc += red[tid * 16 + sg];
        if (*flag) ((float*)out)[b * 10 + tid] = acc;
        else       ((bf16*)out)[b * 10 + tid] = f2b(acc);
    }
}

__global__ void pack_wt_enc(const void* __restrict__ W_enc, bf16* __restrict__ out,
                            const int* __restrict__ flag) {
    int f = *flag;
    int g = blockIdx.x * 256 + threadIdx.x;  // 16384
    int n = g >> 6, k = g & 63;
    out[g] = f2b(ldf(W_enc, (size_t)k * 256 + n, f));
}

extern "C" void kernel_launch(void* const* d_in, const int* in_sizes, int n_in,
                              void* d_out, int out_size, void* d_ws, size_t ws_size,
                              hipStream_t stream) {
    (void)in_sizes; (void)n_in; (void)out_size; (void)ws_size;
    const void* x      = d_in[0];
    const void* W_enc  = d_in[1];
    const void* b_enc  = d_in[2];
    const void* nu_log = d_in[3];
    const void* th_log = d_in[4];
    const void* B_re   = d_in[5];
    const void* B_im   = d_in[6];
    const void* C_re   = d_in[7];
    const void* C_im   = d_in[8];
    const void* Dp     = d_in[9];
    const void* W1     = d_in[10];
    const void* b1     = d_in[11];
    const void* W2     = d_in[12];
    const void* b2     = d_in[13];
    const void* bn_s   = d_in[14];
    const void* bn_b   = d_in[15];
    const void* W_out  = d_in[16];
    const void* b_out  = d_in[17];

    // workspace layout (~171 MB)
    char* w = (char*)d_ws;
    bf16* xc   = (bf16*)w; w += (size_t)MTOT * 256 * 2;
    bf16* y    = (bf16*)w; w += (size_t)MTOT * 256 * 2;
    bf16* lruo = (bf16*)w; w += (size_t)MTOT * 256 * 2;
    bf16* bu   = (bf16*)w; w += (size_t)MTOT * 512 * 2;
    float* bnpart = (float*)w; w += 524288;
    float* carry  = (float*)w; w += 1048576;
    float* pre    = (float*)w; w += 1048576;
    float* part   = (float*)w; w += 524288;
    float* lamb   = (float*)w; w += 12288;
    float* gamt   = (float*)w; w += 6144;
    float* pf     = (float*)w; w += 65536;
    float* st     = (float*)w; w += 2048;
    float* bubias = (float*)w; w += 2048;
    int*   flag   = (int*)w;  w += 256;
    bf16* wt_enc = (bf16*)w; w += 32768;
    bf16* wb  = (bf16*)w; w += 262144;
    bf16* wc  = (bf16*)w; w += 262144;
    bf16* w1t = (bf16*)w; w += 524288;
    bf16* w2t = (bf16*)w; w += 262144;
    bf16* xb = bu;  // x bf16 copy aliases bu (dead until first Bu GEMM)

    dim3 blk(256);
    detect_k<<<1, blk, 0, stream>>>((const unsigned short*)x, flag);
    cvt_k<<<16384, blk, 0, stream>>>(x, xb, 4194304, flag);
    cvtparams<<<60, blk, 0, stream>>>(b_enc, Dp, b1, b2, bn_s, bn_b, W_out, b_out, pf, flag);
    lamgam_k<<<6, blk, 0, stream>>>(nu_log, th_log, lamb, gamt, flag);
    pack_wt_enc<<<64, blk, 0, stream>>>(W_enc, wt_enc, flag);

    // encoder: [M,64] @ W_enc^T + b_enc -> xc and y
    gemm_bt<1><<<dim3(512, 2), blk, 0, stream>>>(xb, 64, wt_enc, 64, xc, y, 256,
                                                 pf + PB_ENC, nullptr, nullptr, nullptr);
    for (int i = 0; i < 6; ++i) {
        bn_part<<<256, blk, 0, stream>>>(xc, bnpart);
        bn_finish<<<1, blk, 0, stream>>>(bnpart, pf, i, st);
        pack_layer<<<2562, blk, 0, stream>>>(B_re, B_im, C_re, C_im, W1, W2, i, st, gamt,
                                             wb, wc, w1t, w2t, bubias, flag);
        // Bu = xc @ (a*gamma*B)^T + bu_bias  (BN folded) -> [M,512]
        gemm_bt<0><<<dim3(512, 4), blk, 0, stream>>>(xc, 256, wb, 256, bu, nullptr, 512,
                                                     bubias, nullptr, nullptr, nullptr);
        lru_carry<<<512, blk, 0, stream>>>(bu, lamb + i * 512, carry);
        lru_prefix<<<32, blk, 0, stream>>>(carry, pre, lamb + i * 512);
        lru_final<<<512, blk, 0, stream>>>(bu, pre, lamb + i * 512);
        // lruo = hs @ [C_re;-C_im]^T + D*(a*xc+c)
        gemm_bt<2><<<dim3(512, 2), blk, 0, stream>>>(bu, 512, wc, 512, lruo, nullptr, 256,
                                                     nullptr, st, pf + PD + i * 256, xc);
        // glu = (lruo@W1v + b1v) * sigmoid(lruo@W1g + b1g) -> bu [M,512]
        gemm_glu<<<dim3(512, 4), blk, 0, stream>>>(lruo, w1t, w1t + 131072, bu,
                                                   pf + PB1 + i * 1024);
        // xc = glu @ W2^T + b2 + y
        gemm_bt<5><<<dim3(512, 2), blk, 0, stream>>>(bu, 512, w2t, 512, xc, nullptr, 256,
                                                     pf + PB2 + i * 256, nullptr, nullptr, y);
    }
    pool_part<<<512, blk, 0, stream>>>(xc, part);
    head_k<<<32, blk, 0, stream>>>(part, pf, d_out, flag);
}

// Round 6
// 1949.859 us; speedup vs baseline: 1.1854x; 1.0516x over previous
//
#include <hip/hip_runtime.h>
#include <hip/hip_bf16.h>
#include <math.h>

using bf16 = __hip_bfloat16;
typedef __attribute__((ext_vector_type(8))) short s8v;
typedef __attribute__((ext_vector_type(4))) short s4v;
typedef __attribute__((ext_vector_type(2))) short s2v;
typedef __attribute__((ext_vector_type(4))) float f4v;

#define MTOT 65536   // B*T
#define TLEN 2048
#define NCHUNK 16
#define TCH 128

// params-table float offsets
#define PB_ENC 0
#define PD     256
#define PB1    1792
#define PB2    7936
#define PBNS   9472
#define PBNB   11008
#define PWOUT  12544
#define PBOUT  15104
#define PTOT   15114

__device__ __forceinline__ float b2f(bf16 x) { return __bfloat162float(x); }
__device__ __forceinline__ bf16 f2b(float x) { return __float2bfloat16(x); }

__device__ __forceinline__ float ldf(const void* p, size_t i, int f) {
    return f ? ((const float*)p)[i] : b2f(((const bf16*)p)[i]);
}

__device__ __forceinline__ void ld_g2l(const void* g, void* l) {
    __builtin_amdgcn_global_load_lds(
        (const __attribute__((address_space(1))) void*)g,
        (__attribute__((address_space(3))) void*)l,
        16, 0, 0);
}

// ---------------- dtype detection ----------------
__global__ void detect_k(const unsigned short* __restrict__ x, int* __restrict__ flag) {
    int tid = threadIdx.x;
    int cnt = 0;
    for (int i = tid; i < 8192; i += 256) {
        int e = (x[i] >> 7) & 0xFF;
        if (e == 0 || e == 0xFF) cnt++;
    }
    __shared__ int red[256];
    red[tid] = cnt;
    __syncthreads();
    for (int s = 128; s > 0; s >>= 1) {
        if (tid < s) red[tid] += red[tid + s];
        __syncthreads();
    }
    if (tid == 0) flag[0] = (red[0] >= 2) ? 1 : 0;
}

__global__ void cvt_k(const void* __restrict__ src, bf16* __restrict__ dst, int n,
                      const int* __restrict__ flag) {
    int f = *flag;
    int i = blockIdx.x * 256 + threadIdx.x;
    if (i < n) dst[i] = f2b(ldf(src, i, f));
}

// all small params -> fp32 table
__global__ void cvtparams(const void* b_enc, const void* Dp, const void* b1,
                          const void* b2, const void* bn_s, const void* bn_b,
                          const void* W_out, const void* b_out,
                          float* __restrict__ pf, const int* __restrict__ flag) {
    int f = *flag;
    int i = blockIdx.x * 256 + threadIdx.x;
    if (i < 256)        pf[i] = ldf(b_enc, i, f);
    else if (i < 1792)  pf[i] = ldf(Dp, i - 256, f);
    else if (i < 7936)  pf[i] = ldf(b1, i - 1792, f);
    else if (i < 9472)  pf[i] = ldf(b2, i - 7936, f);
    else if (i < 11008) pf[i] = ldf(bn_s, i - 9472, f);
    else if (i < 12544) pf[i] = ldf(bn_b, i - 11008, f);
    else if (i < 15104) pf[i] = ldf(W_out, i - 12544, f);
    else if (i < PTOT)  pf[i] = ldf(b_out, i - 15104, f);
}

// lambda (fp32) + gamma tables for all 6 layers
__global__ void lamgam_k(const void* __restrict__ nu, const void* __restrict__ th,
                         float* __restrict__ lamb, float* __restrict__ gamt,
                         const int* __restrict__ flag) {
    int f = *flag;
    int g = blockIdx.x * 256 + threadIdx.x;  // 1536
    float nl = ldf(nu, g, f), tl = ldf(th, g, f);
    float mag = expf(-expf(nl));
    float ang = expf(tl);
    lamb[g * 2] = mag * cosf(ang);
    lamb[g * 2 + 1] = mag * sinf(ang);
    gamt[g] = sqrtf(fmaxf(1.f - mag * mag, 1e-12f));
}

// ---------------- GEMM: out[m,n] = sum_k A[m,k]*W[n,k] + epilogue ----------
// 128x128 tile, BK=64, 16x16x32 MFMA, swapped operands (C^T register layout:
// lane holds m fixed, 4 consecutive n). Double-buffered LDS (A+W x2, 64 KB),
// ONE barrier per K-iter: loads for kt+1 issue right after the barrier and
// have the whole compute(kt) phase to land before the next vmcnt(0) drain.
// EPI 0: +biasF -> bf16                         (Bu, BN-folded bias)
// EPI 1: +biasF -> bf16 outB AND outB2          (encoder -> xc, y)
// EPI 2: +Dv[n]*(st_a[n]*aux+st_c[n]) -> bf16   (LRU C-out, BN-folded D-term)
// EPI 5: +biasF + aux -> bf16                   (W2 + residual y -> xc)
// EPI 6: GLU: n'-space val/gate interleaved; out[m, n'>>1] = val*sigmoid(gate)
template<int EPI>
__global__ __launch_bounds__(256)
void gemm_bt(const bf16* __restrict__ A, int lda,
             const bf16* __restrict__ W, int K,
             bf16* __restrict__ outB, bf16* __restrict__ outB2, int ldo,
             const float* __restrict__ biasF,
             const float* __restrict__ st,
             const float* __restrict__ Dv,
             const bf16* __restrict__ aux)
{
    const int bm = blockIdx.x, bn = blockIdx.y;
    const int tid = threadIdx.x;
    const int lane = tid & 63, wv = tid >> 6;
    const int wm = wv >> 1, wn = wv & 1;
    const int quad = lane >> 4, cl = lane & 15;

    __shared__ __align__(16) short As[2][8192];
    __shared__ __align__(16) short Ws[2][8192];

    f4v acc[4][4];
#pragma unroll
    for (int i = 0; i < 4; i++)
#pragma unroll
        for (int j = 0; j < 4; j++) acc[i][j] = (f4v){0.f, 0.f, 0.f, 0.f};

    const char* Abase = (const char*)(A + (size_t)bm * 128 * lda);
    const char* Wbase = (const char*)(W + (size_t)bn * 128 * K);
    const int rsub = lane >> 3;
    const int swz = ((lane & 7) ^ rsub) * 16;
    const int ldab = lda * 2, kb = K * 2;

    auto stage = [&](int kt, int buf) {
#pragma unroll
        for (int p = 0; p < 4; ++p) {
            int seg = p * 4 + wv;
            ld_g2l(Abase + (size_t)(seg * 8 + rsub) * ldab + kt * 128 + swz,
                   (char*)&As[buf][seg * 512]);
            ld_g2l(Wbase + (size_t)(seg * 8 + rsub) * kb + kt * 128 + swz,
                   (char*)&Ws[buf][seg * 512]);
        }
    };

    const int nk = K >> 6;
    stage(0, 0);
    for (int kt = 0; kt < nk; ++kt) {
        __syncthreads();               // drains loads(kt); compute(kt-1) done by all
        if (kt + 1 < nk) stage(kt + 1, (kt + 1) & 1);
        const int buf = kt & 1;
#pragma unroll
        for (int kk = 0; kk < 2; ++kk) {
            s8v af[4], bfr[4];
#pragma unroll
            for (int i = 0; i < 4; i++) {
                int r = wm * 64 + i * 16 + cl;
                int poff = (((kk * 4 + quad) ^ (r & 7)) * 8);
                af[i] = *(const s8v*)&As[buf][r * 64 + poff];
            }
#pragma unroll
            for (int j = 0; j < 4; j++) {
                int r = wn * 64 + j * 16 + cl;
                int poff = (((kk * 4 + quad) ^ (r & 7)) * 8);
                bfr[j] = *(const s8v*)&Ws[buf][r * 64 + poff];
            }
            // swapped operands: acc = W_frag * A_frag -> C^T tile layout
#pragma unroll
            for (int i = 0; i < 4; i++)
#pragma unroll
                for (int j = 0; j < 4; j++)
                    acc[i][j] = __builtin_amdgcn_mfma_f32_16x16x32_bf16(bfr[j], af[i], acc[i][j], 0, 0, 0);
        }
    }

    // register-direct epilogue: lane holds m = mBase+i*16, n = nBase+j*16+{0..3}
    const size_t ld = (size_t)ldo;
    const int mBase = bm * 128 + wm * 64 + cl;
    const int nBase = bn * 128 + wn * 64 + quad * 4;
#pragma unroll
    for (int j = 0; j < 4; j++) {
        const int n = nBase + j * 16;
        if (EPI == 6) {
            const int c = n >> 1;  // n multiple of 4 -> c multiple of 2
            float bv0 = biasF[c], bv1 = biasF[c + 1];
            float bg0 = biasF[512 + c], bg1 = biasF[513 + c];
#pragma unroll
            for (int i = 0; i < 4; i++) {
                const int m = mBase + i * 16;
                float v0 = acc[i][j][0] + bv0, g0 = acc[i][j][1] + bg0;
                float v1 = acc[i][j][2] + bv1, g1 = acc[i][j][3] + bg1;
                s2v o;
                ((bf16*)&o)[0] = f2b(v0 / (1.f + expf(-g0)));
                ((bf16*)&o)[1] = f2b(v1 / (1.f + expf(-g1)));
                *(s2v*)(outB + (size_t)m * ld + c) = o;
            }
        } else {
            f4v bb, dv, sa, sc;
            if (EPI == 0 || EPI == 1 || EPI == 5) bb = *(const f4v*)(biasF + n);
            if (EPI == 2) {
                dv = *(const f4v*)(Dv + n);
                sa = *(const f4v*)(st + n);
                sc = *(const f4v*)(st + 256 + n);
            }
#pragma unroll
            for (int i = 0; i < 4; i++) {
                const int m = mBase + i * 16;
                const size_t idx = (size_t)m * ld + n;
                f4v v = acc[i][j];
                if (EPI == 0 || EPI == 1 || EPI == 5) {
#pragma unroll
                    for (int e = 0; e < 4; e++) v[e] += bb[e];
                }
                if (EPI == 2) {
                    s4v a = *(const s4v*)(aux + idx);
#pragma unroll
                    for (int e = 0; e < 4; e++)
                        v[e] += dv[e] * (sa[e] * b2f(((const bf16*)&a)[e]) + sc[e]);
                }
                if (EPI == 5) {
                    s4v a = *(const s4v*)(aux + idx);
#pragma unroll
                    for (int e = 0; e < 4; e++) v[e] += b2f(((const bf16*)&a)[e]);
                }
                s4v o;
#pragma unroll
                for (int e = 0; e < 4; e++) ((bf16*)&o)[e] = f2b(v[e]);
                *(s4v*)(outB + idx) = o;
                if (EPI == 1) *(s4v*)(outB2 + idx) = o;
            }
        }
    }
}

// ---------------- BatchNorm stats (two-pass, transposed partials) ----------
__global__ void bn_part(const bf16* __restrict__ x, float* __restrict__ part) {
    int e = threadIdx.x, b = blockIdx.x;  // 256 blocks
    size_t base = (size_t)b * 256;
    float s = 0.f, s2 = 0.f;
    for (int r = 0; r < 256; r++) {
        float v = b2f(x[(base + r) * 256 + e]);
        s += v; s2 += v * v;
    }
    part[(size_t)e * 256 + b] = s;
    part[65536 + (size_t)e * 256 + b] = s2;
}

// st[0..255] = a (scale), st[256..511] = c (offset):  BN(x)[e] = a[e]*x + c[e]
__global__ void bn_finish(const float* __restrict__ part, const float* __restrict__ pf,
                          int layer, float* __restrict__ st) {
    int e = threadIdx.x;
    const float* p1 = part + (size_t)e * 256;
    const float* p2 = part + 65536 + (size_t)e * 256;
    float s = 0.f, s2 = 0.f;
    for (int b = 0; b < 256; b += 4) {
        f4v t1 = *(const f4v*)(p1 + b);
        f4v t2 = *(const f4v*)(p2 + b);
        s += t1[0] + t1[1] + t1[2] + t1[3];
        s2 += t2[0] + t2[1] + t2[2] + t2[3];
    }
    float mu = s * (1.f / 65536.f);
    float var = s2 * (1.f / 65536.f) - mu * mu;
    float a = rsqrtf(var + 1e-5f) * pf[PBNS + layer * 256 + e];
    st[e] = a;
    st[256 + e] = pf[PBNB + layer * 256 + e] - mu * a;
}

// ---------------- per-layer weight packing (single dispatch) ----------------
// blocks 0..511: wb (BN-scale folded), 512..1023: wc, 1024..2047: w1t
// (val/gate INTERLEAVED: row 2c = W1 col c, row 2c+1 = W1 col 512+c),
// 2048..2559: w2t, 2560..2561: bu_bias
__global__ void pack_layer(const void* __restrict__ B_re, const void* __restrict__ B_im,
                           const void* __restrict__ C_re, const void* __restrict__ C_im,
                           const void* __restrict__ W1, const void* __restrict__ W2,
                           int layer, const float* __restrict__ st,
                           const float* __restrict__ gamt,
                           bf16* __restrict__ wb, bf16* __restrict__ wc,
                           bf16* __restrict__ w1t, bf16* __restrict__ w2t,
                           float* __restrict__ bubias, const int* __restrict__ flag) {
    int f = *flag;
    int blk = blockIdx.x, tid = threadIdx.x;
    size_t offBC = (size_t)layer * 65536;
    if (blk < 512) {
        int g = blk * 256 + tid;
        int n = g >> 8, e = g & 255, h = n & 255;
        const void* src = (n < 256) ? B_re : B_im;
        wb[g] = f2b(st[e] * gamt[layer * 256 + h] * ldf(src, offBC + (size_t)h * 256 + e, f));
    } else if (blk < 1024) {
        int g = (blk - 512) * 256 + tid;
        int e = g >> 9, k = g & 511;
        float v = (k < 256) ? ldf(C_re, offBC + (size_t)e * 256 + k, f)
                            : -ldf(C_im, offBC + (size_t)e * 256 + (k - 256), f);
        wc[g] = f2b(v);
    } else if (blk < 2048) {
        int g = (blk - 1024) * 256 + tid;
        int np = g >> 8, k = g & 255;           // np = interleaved row 0..1023
        int l = (np >> 1) + (np & 1) * 512;     // source col in W1
        w1t[g] = f2b(ldf(W1, (size_t)layer * 262144 + (size_t)k * 1024 + l, f));
    } else if (blk < 2560) {
        int g = (blk - 2048) * 256 + tid;
        int n = g >> 9, k = g & 511;
        w2t[g] = f2b(ldf(W2, (size_t)layer * 131072 + (size_t)k * 256 + n, f));
    } else {
        int n = (blk - 2560) * 256 + tid;  // 0..511
        int h = n & 255;
        const void* src = (n < 256) ? B_re : B_im;
        float gam = gamt[layer * 256 + h];
        float s = 0.f;
        for (int e = 0; e < 256; e++)
            s += st[256 + e] * ldf(src, offBC + (size_t)h * 256 + e, f);
        bubias[n] = s * gam;
    }
}

// ---------------- LRU scan (chunked, in-place over bu) ----------------
__global__ void lru_carry(const bf16* __restrict__ bu, const float* __restrict__ lam,
                          float* __restrict__ carry) {
    int g = blockIdx.x * 256 + threadIdx.x;
    int h = g & 255, c = (g >> 8) & 15, b = g >> 12;
    float lr = lam[h * 2], li = lam[h * 2 + 1];
    float sr = 0.f, si = 0.f;
    const bf16* p = bu + ((size_t)(b * TLEN + c * TCH)) * 512 + h;
    for (int t = 0; t < TCH; t++) {
        float ur = b2f(p[0]), ui = b2f(p[256]);
        float nr = lr * sr - li * si + ur;
        si = lr * si + li * sr + ui;
        sr = nr;
        p += 512;
    }
    carry[(size_t)g * 2] = sr;
    carry[(size_t)g * 2 + 1] = si;
}

__global__ void lru_prefix(const float* __restrict__ carry, float* __restrict__ pre,
                           const float* __restrict__ lam) {
    int g = blockIdx.x * 256 + threadIdx.x;  // 8192
    int h = g & 255, b = g >> 8;
    float pr = lam[h * 2], pi = lam[h * 2 + 1];
    for (int k = 0; k < 7; k++) { float nr = pr * pr - pi * pi; pi = 2.f * pr * pi; pr = nr; }
    float er = 0.f, ei = 0.f;
    for (int c = 0; c < NCHUNK; c++) {
        size_t idx = ((size_t)(b * NCHUNK + c) * 256 + h) * 2;
        pre[idx] = er; pre[idx + 1] = ei;
        float cr = carry[idx], ci = carry[idx + 1];
        float nr = pr * er - pi * ei + cr;
        ei = pr * ei + pi * er + ci;
        er = nr;
    }
}

__global__ void lru_final(bf16* __restrict__ bu, const float* __restrict__ pre,
                          const float* __restrict__ lam) {
    int g = blockIdx.x * 256 + threadIdx.x;
    int h = g & 255, c = (g >> 8) & 15, b = g >> 12;
    float lr = lam[h * 2], li = lam[h * 2 + 1];
    float sr = pre[(size_t)g * 2], si = pre[(size_t)g * 2 + 1];
    bf16* p = bu + ((size_t)(b * TLEN + c * TCH)) * 512 + h;
    for (int t = 0; t < TCH; t++) {
        float ur = b2f(p[0]), ui = b2f(p[256]);
        float nr = lr * sr - li * si + ur;
        si = lr * si + li * sr + ui;
        sr = nr;
        p[0] = f2b(sr);
        p[256] = f2b(si);
        p += 512;
    }
}

// ---------------- pooling + head ----------------
__global__ void pool_part(const bf16* __restrict__ xc, float* __restrict__ part) {
    int blk = blockIdx.x;  // 512
    int b = blk >> 4, tc = blk & 15;
    int e = threadIdx.x;
    const bf16* p = xc + ((size_t)b * TLEN + tc * TCH) * 256 + e;
    float s = 0.f;
    for (int r = 0; r < TCH; r++) { s += b2f(*p); p += 256; }
    part[(size_t)blk * 256 + e] = s;
}

__global__ void head_k(const float* __restrict__ part, const float* __restrict__ pf,
                       void* __restrict__ out, const int* __restrict__ flag) {
    int b = blockIdx.x;
    int tid = threadIdx.x;
    __shared__ float sp[256];
    __shared__ float red[160];
    float s = 0.f;
    for (int c = 0; c < 16; c++) s += part[((size_t)(b * 16 + c)) * 256 + tid];
    sp[tid] = s * (1.f / 2048.f);
    __syncthreads();
    if (tid < 160) {
        int o = tid >> 4, sg = tid & 15;
        float a = 0.f;
        for (int e = sg; e < 256; e += 16) a += sp[e] * pf[PWOUT + e * 10 + o];
        red[tid] = a;
    }
    __syncthreads();
    if (tid < 10) {
        float acc = pf[PBOUT + tid];
        for (int sg = 0; sg < 16; sg++) acc += red[tid * 16 + sg];
        if (*flag) ((float*)out)[b * 10 + tid] = acc;
        else       ((bf16*)out)[b * 10 + tid] = f2b(acc);
    }
}

__global__ void pack_wt_enc(const void* __restrict__ W_enc, bf16* __restrict__ out,
                            const int* __restrict__ flag) {
    int f = *flag;
    int g = blockIdx.x * 256 + threadIdx.x;  // 16384
    int n = g >> 6, k = g & 63;
    out[g] = f2b(ldf(W_enc, (size_t)k * 256 + n, f));
}

extern "C" void kernel_launch(void* const* d_in, const int* in_sizes, int n_in,
                              void* d_out, int out_size, void* d_ws, size_t ws_size,
                              hipStream_t stream) {
    (void)in_sizes; (void)n_in; (void)out_size; (void)ws_size;
    const void* x      = d_in[0];
    const void* W_enc  = d_in[1];
    const void* b_enc  = d_in[2];
    const void* nu_log = d_in[3];
    const void* th_log = d_in[4];
    const void* B_re   = d_in[5];
    const void* B_im   = d_in[6];
    const void* C_re   = d_in[7];
    const void* C_im   = d_in[8];
    const void* Dp     = d_in[9];
    const void* W1     = d_in[10];
    const void* b1     = d_in[11];
    const void* W2     = d_in[12];
    const void* b2     = d_in[13];
    const void* bn_s   = d_in[14];
    const void* bn_b   = d_in[15];
    const void* W_out  = d_in[16];
    const void* b_out  = d_in[17];

    // workspace layout (~171 MB)
    char* w = (char*)d_ws;
    bf16* xc   = (bf16*)w; w += (size_t)MTOT * 256 * 2;
    bf16* y    = (bf16*)w; w += (size_t)MTOT * 256 * 2;
    bf16* lruo = (bf16*)w; w += (size_t)MTOT * 256 * 2;
    bf16* bu   = (bf16*)w; w += (size_t)MTOT * 512 * 2;
    float* bnpart = (float*)w; w += 524288;
    float* carry  = (float*)w; w += 1048576;
    float* pre    = (float*)w; w += 1048576;
    float* part   = (float*)w; w += 524288;
    float* lamb   = (float*)w; w += 12288;
    float* gamt   = (float*)w; w += 6144;
    float* pf     = (float*)w; w += 65536;
    float* st     = (float*)w; w += 2048;
    float* bubias = (float*)w; w += 2048;
    int*   flag   = (int*)w;  w += 256;
    bf16* wt_enc = (bf16*)w; w += 32768;
    bf16* wb  = (bf16*)w; w += 262144;
    bf16* wc  = (bf16*)w; w += 262144;
    bf16* w1t = (bf16*)w; w += 524288;
    bf16* w2t = (bf16*)w; w += 262144;
    bf16* xb = bu;  // x bf16 copy aliases bu (dead until first Bu GEMM)

    dim3 blk(256);
    detect_k<<<1, blk, 0, stream>>>((const unsigned short*)x, flag);
    cvt_k<<<16384, blk, 0, stream>>>(x, xb, 4194304, flag);
    cvtparams<<<60, blk, 0, stream>>>(b_enc, Dp, b1, b2, bn_s, bn_b, W_out, b_out, pf, flag);
    lamgam_k<<<6, blk, 0, stream>>>(nu_log, th_log, lamb, gamt, flag);
    pack_wt_enc<<<64, blk, 0, stream>>>(W_enc, wt_enc, flag);

    // encoder: [M,64] @ W_enc^T + b_enc -> xc and y
    gemm_bt<1><<<dim3(512, 2), blk, 0, stream>>>(xb, 64, wt_enc, 64, xc, y, 256,
                                                 pf + PB_ENC, nullptr, nullptr, nullptr);
    for (int i = 0; i < 6; ++i) {
        bn_part<<<256, blk, 0, stream>>>(xc, bnpart);
        bn_finish<<<1, blk, 0, stream>>>(bnpart, pf, i, st);
        pack_layer<<<2562, blk, 0, stream>>>(B_re, B_im, C_re, C_im, W1, W2, i, st, gamt,
                                             wb, wc, w1t, w2t, bubias, flag);
        // Bu = xc @ (a*gamma*B)^T + bu_bias  (BN folded) -> [M,512]
        gemm_bt<0><<<dim3(512, 4), blk, 0, stream>>>(xc, 256, wb, 256, bu, nullptr, 512,
                                                     bubias, nullptr, nullptr, nullptr);
        lru_carry<<<512, blk, 0, stream>>>(bu, lamb + i * 512, carry);
        lru_prefix<<<32, blk, 0, stream>>>(carry, pre, lamb + i * 512);
        lru_final<<<512, blk, 0, stream>>>(bu, pre, lamb + i * 512);
        // lruo = hs @ [C_re;-C_im]^T + D*(a*xc+c)
        gemm_bt<2><<<dim3(512, 2), blk, 0, stream>>>(bu, 512, wc, 512, lruo, nullptr, 256,
                                                     nullptr, st, pf + PD + i * 256, xc);
        // glu: interleaved val/gate GEMM over n'=1024 -> bu [M,512]
        gemm_bt<6><<<dim3(512, 8), blk, 0, stream>>>(lruo, 256, w1t, 256, bu, nullptr, 512,
                                                     pf + PB1 + i * 1024, nullptr, nullptr, nullptr);
        // xc = glu @ W2^T + b2 + y
        gemm_bt<5><<<dim3(512, 2), blk, 0, stream>>>(bu, 512, w2t, 512, xc, nullptr, 256,
                                                     pf + PB2 + i * 256, nullptr, nullptr, y);
    }
    pool_part<<<512, blk, 0, stream>>>(xc, part);
    head_k<<<32, blk, 0, stream>>>(part, pf, d_out, flag);
}